// Round 13
// baseline (51.037 us; speedup 1.0000x reference)
//
#include <hip/hip_runtime.h>

#define BB 8
#define HH 512
#define WW 512
#define HW (HH * WW)

typedef float f32x2 __attribute__((ext_vector_type(2)));

__device__ __forceinline__ int reflect512(int v) {
    v = v < 0 ? -v : v;
    return v >= 512 ? 1022 - v : v;
}

// unnormalized 1-D spatial gaussian (sigma=21); out-of-window -> 0 (mask)
__device__ __forceinline__ float swx(int dx) {
    const float SW[7] = {0.98984784f, 0.99547514f, 0.99886688f, 1.0f,
                         0.99886688f, 0.99547514f, 0.98984784f};
    return (dx < -3 || dx > 3) ? 0.0f : SW[dx + 3];
}

// exp(-0.005*d2) ~= 1 + C1*d2 + C2*d2^2, |err| <= 1.5e-5 for d<=3 (R5-proven)
#define C1S (-5.0e-3f)
#define C2S (1.25e-5f)

__global__ __launch_bounds__(256) void bilateral_pk2(const float* __restrict__ in,
                                                     float* __restrict__ out) {
    const int blk = blockIdx.x;
    if (blk < BB * HH) {
        // ---- interior: thread owns pixels (y, e-1)=A and (y, e)=B ----
        const int b = blk >> 9;
        const int y = blk & 511;
        const int p = threadIdx.x;
        if (p >= 253) return;            // cols 3..508 here; no barriers used
        const int e  = 4 + 2 * p;
        const int xb = e - 4;            // leftmost loaded col (even, 8B aligned)

        const float* __restrict__ p0 = in + (size_t)(3 * b) * HW;
        const float* __restrict__ p1 = p0 + HW;
        const float* __restrict__ p2 = p1 + HW;

        const int crow = y * WW;
        f32x2 m0 = *(const f32x2*)(p0 + crow + e - 2);   // cols e-2,e-1
        f32x2 m1 = *(const f32x2*)(p1 + crow + e - 2);
        f32x2 m2 = *(const f32x2*)(p2 + crow + e - 2);
        f32x2 g0 = *(const f32x2*)(p0 + crow + e);       // cols e,e+1
        f32x2 g1 = *(const f32x2*)(p1 + crow + e);
        f32x2 g2 = *(const f32x2*)(p2 + crow + e);
        const float cA0 = m0.y, cA1 = m1.y, cA2 = m2.y;
        const float cB0 = g0.x, cB1 = g1.x, cB2 = g2.x;

        f32x2 aA0 = {0.f,0.f}, aA1 = {0.f,0.f}, aA2 = {0.f,0.f}, aAd = {0.f,0.f};
        f32x2 aB0 = {0.f,0.f}, aB1 = {0.f,0.f}, aB2 = {0.f,0.f}, aBd = {0.f,0.f};

        const f32x2 C1v = {C1S, C1S};
        const f32x2 C2v = {C2S, C2S};
        const f32x2 ONE = {1.0f, 1.0f};

        #pragma unroll
        for (int j = 0; j < 7; ++j) {
            const float wj = swx(j - 3);
            const int rb = reflect512(y - 3 + j) * WW + xb;
            const float* r0 = p0 + rb;
            const float* r1 = p1 + rb;
            const float* r2 = p2 + rb;
            #pragma unroll
            for (int i = 0; i < 4; ++i) {
                f32x2 q0 = *(const f32x2*)(r0 + 2 * i);
                f32x2 q1 = *(const f32x2*)(r1 + 2 * i);
                f32x2 q2 = *(const f32x2*)(r2 + 2 * i);
                {   // pixel A: dx = {2i-3, 2i-2}; sc=0 masks dx=4
                    float dlo = fabsf(q0.x-cA0) + fabsf(q1.x-cA1) + fabsf(q2.x-cA2);
                    float dhi = fabsf(q0.y-cA0) + fabsf(q1.y-cA1) + fabsf(q2.y-cA2);
                    f32x2 dp = {dlo, dhi};
                    f32x2 d2 = dp * dp;
                    const f32x2 sc = {wj * swx(2*i-3), wj * swx(2*i-2)};
                    f32x2 t = C2v * d2 + C1v;          // pk_fma (ffp-contract)
                    f32x2 w = (t * d2 + ONE) * sc;     // pk_fma + pk_mul
                    aA0 += w * q0; aA1 += w * q1; aA2 += w * q2; aAd += w;
                }
                {   // pixel B: dx = {2i-4, 2i-3}; sc=0 masks dx=-4
                    float dlo = fabsf(q0.x-cB0) + fabsf(q1.x-cB1) + fabsf(q2.x-cB2);
                    float dhi = fabsf(q0.y-cB0) + fabsf(q1.y-cB1) + fabsf(q2.y-cB2);
                    f32x2 dp = {dlo, dhi};
                    f32x2 d2 = dp * dp;
                    const f32x2 sc = {wj * swx(2*i-4), wj * swx(2*i-3)};
                    f32x2 t = C2v * d2 + C1v;
                    f32x2 w = (t * d2 + ONE) * sc;
                    aB0 += w * q0; aB1 += w * q1; aB2 += w * q2; aBd += w;
                }
            }
        }

        const float iA = 1.0f / (aAd.x + aAd.y);
        const float iB = 1.0f / (aBd.x + aBd.y);
        size_t ob = (size_t)(3 * b) * HW + crow;
        out[ob + e - 1]          = (aA0.x + aA0.y) * iA;
        out[ob + HW + e - 1]     = (aA1.x + aA1.y) * iA;
        out[ob + 2 * HW + e - 1] = (aA2.x + aA2.y) * iA;
        out[ob + e]              = (aB0.x + aB0.y) * iB;
        out[ob + HW + e]         = (aB1.x + aB1.y) * iB;
        out[ob + 2 * HW + e]     = (aB2.x + aB2.y) * iB;
    } else {
        // ---- border path: columns {0,1,2,509,510,511}, all rows/batches ----
        int idx  = (blk - BB * HH) * 256 + threadIdx.x;   // exactly 24576 total
        int ci   = idx % 6;
        int rest = idx / 6;
        int y = rest & 511;
        int b = rest >> 9;
        int x = ci < 3 ? ci : 506 + ci;

        const float* __restrict__ p0 = in + (size_t)(3 * b) * HW;
        const float* __restrict__ p1 = p0 + HW;
        const float* __restrict__ p2 = p1 + HW;
        int cidx = y * WW + x;
        float c0 = p0[cidx], c1 = p1[cidx], c2 = p2[cidx];
        float n0 = 0.f, n1 = 0.f, n2 = 0.f, dn = 0.f;
        #pragma unroll
        for (int dy = 0; dy < 7; ++dy) {
            int rbase = reflect512(y + dy - 3) * WW;
            float wy = swx(dy - 3);
            #pragma unroll
            for (int dx = 0; dx < 7; ++dx) {
                int o = rbase + reflect512(x + dx - 3);
                float q0 = p0[o], q1 = p1[o], q2 = p2[o];
                float d  = fabsf(q0 - c0) + fabsf(q1 - c1) + fabsf(q2 - c2);
                float d2 = d * d;
                float w  = wy * swx(dx - 3) * fmaf(fmaf(C2S, d2, C1S), d2, 1.0f);
                n0 += w * q0; n1 += w * q1; n2 += w * q2; dn += w;
            }
        }
        float inv = 1.0f / dn;
        size_t ob = (size_t)(3 * b) * HW + cidx;
        out[ob] = n0 * inv; out[ob + HW] = n1 * inv; out[ob + 2 * HW] = n2 * inv;
    }
}

extern "C" void kernel_launch(void* const* d_in, const int* in_sizes, int n_in,
                              void* d_out, int out_size, void* d_ws, size_t ws_size,
                              hipStream_t stream) {
    const float* in = (const float*)d_in[0];
    float* out = (float*)d_out;
    // 4096 interior blocks (one per image row) + 96 border blocks
    int blocks = BB * HH + (BB * HH * 6) / 256;   // 4096 + 96 = 4192
    bilateral_pk2<<<blocks, 256, 0, stream>>>(in, out);
}

// Round 14
// 48.845 us; speedup vs baseline: 1.0449x; 1.0449x over previous
//
#include <hip/hip_runtime.h>

#define BB 8
#define HH 512
#define WW 512
#define HW (HH * WW)

typedef float f32x2 __attribute__((ext_vector_type(2)));

__device__ __forceinline__ int reflect512(int v) {
    v = v < 0 ? -v : v;
    return v >= 512 ? 1022 - v : v;
}

// unnormalized 1-D spatial gaussian (sigma=21); out-of-window -> 0 (mask)
__device__ __forceinline__ float swx(int dx) {
    const float SW[7] = {0.98984784f, 0.99547514f, 0.99886688f, 1.0f,
                         0.99886688f, 0.99547514f, 0.98984784f};
    return (dx < -3 || dx > 3) ? 0.0f : SW[dx + 3];
}

// exp(-0.005*d2) ~= 1 + C1*d2 + C2*d2^2, |err| <= 1.5e-5 for d<=3 (R5-proven)
#define C1S (-5.0e-3f)
#define C2S (1.25e-5f)

__global__ __launch_bounds__(256) void bilateral_pk2(const float* __restrict__ in,
                                                     float* __restrict__ out) {
    const int blk = blockIdx.x;
    if (blk < BB * HH) {
        // ---- XCD-aware swizzle: HW round-robins block->XCD by blk%8, so
        // XCD k gets image k with rows in y-order; overlapping 7-row windows
        // then hit the same per-XCD L2 instead of re-fetching HBM (R13:
        // FETCH 89 MB = 3.6x input without this).
        const int swz = (blk & 7) * (BB * HH / 8) + (blk >> 3);
        const int b = swz >> 9;
        const int y = swz & 511;
        const int p = threadIdx.x;
        if (p >= 253) return;            // cols 3..508 here; no barriers used
        const int e  = 4 + 2 * p;        // thread owns pixels A=(y,e-1), B=(y,e)
        const int xb = e - 4;            // leftmost loaded col (even, 8B aligned)

        const float* __restrict__ p0 = in + (size_t)(3 * b) * HW;
        const float* __restrict__ p1 = p0 + HW;
        const float* __restrict__ p2 = p1 + HW;

        const int crow = y * WW;
        f32x2 m0 = *(const f32x2*)(p0 + crow + e - 2);   // cols e-2,e-1
        f32x2 m1 = *(const f32x2*)(p1 + crow + e - 2);
        f32x2 m2 = *(const f32x2*)(p2 + crow + e - 2);
        f32x2 g0 = *(const f32x2*)(p0 + crow + e);       // cols e,e+1
        f32x2 g1 = *(const f32x2*)(p1 + crow + e);
        f32x2 g2 = *(const f32x2*)(p2 + crow + e);
        const float cA0 = m0.y, cA1 = m1.y, cA2 = m2.y;
        const float cB0 = g0.x, cB1 = g1.x, cB2 = g2.x;

        f32x2 aA0 = {0.f,0.f}, aA1 = {0.f,0.f}, aA2 = {0.f,0.f}, aAd = {0.f,0.f};
        f32x2 aB0 = {0.f,0.f}, aB1 = {0.f,0.f}, aB2 = {0.f,0.f}, aBd = {0.f,0.f};

        const f32x2 C1v = {C1S, C1S};
        const f32x2 C2v = {C2S, C2S};
        const f32x2 ONE = {1.0f, 1.0f};

        #pragma unroll
        for (int j = 0; j < 7; ++j) {
            const float wj = swx(j - 3);
            const int rb = reflect512(y - 3 + j) * WW + xb;
            const float* r0 = p0 + rb;
            const float* r1 = p1 + rb;
            const float* r2 = p2 + rb;
            #pragma unroll
            for (int i = 0; i < 4; ++i) {
                f32x2 q0 = *(const f32x2*)(r0 + 2 * i);
                f32x2 q1 = *(const f32x2*)(r1 + 2 * i);
                f32x2 q2 = *(const f32x2*)(r2 + 2 * i);
                {   // pixel A: dx = {2i-3, 2i-2}; sc=0 masks dx=4
                    float dlo = fabsf(q0.x-cA0) + fabsf(q1.x-cA1) + fabsf(q2.x-cA2);
                    float dhi = fabsf(q0.y-cA0) + fabsf(q1.y-cA1) + fabsf(q2.y-cA2);
                    f32x2 dp = {dlo, dhi};
                    f32x2 d2 = dp * dp;
                    const f32x2 sc = {wj * swx(2*i-3), wj * swx(2*i-2)};
                    f32x2 t = C2v * d2 + C1v;          // pk_fma (ffp-contract)
                    f32x2 w = (t * d2 + ONE) * sc;     // pk_fma + pk_mul
                    aA0 += w * q0; aA1 += w * q1; aA2 += w * q2; aAd += w;
                }
                {   // pixel B: dx = {2i-4, 2i-3}; sc=0 masks dx=-4
                    float dlo = fabsf(q0.x-cB0) + fabsf(q1.x-cB1) + fabsf(q2.x-cB2);
                    float dhi = fabsf(q0.y-cB0) + fabsf(q1.y-cB1) + fabsf(q2.y-cB2);
                    f32x2 dp = {dlo, dhi};
                    f32x2 d2 = dp * dp;
                    const f32x2 sc = {wj * swx(2*i-4), wj * swx(2*i-3)};
                    f32x2 t = C2v * d2 + C1v;
                    f32x2 w = (t * d2 + ONE) * sc;
                    aB0 += w * q0; aB1 += w * q1; aB2 += w * q2; aBd += w;
                }
            }
        }

        const float iA = 1.0f / (aAd.x + aAd.y);
        const float iB = 1.0f / (aBd.x + aBd.y);
        size_t ob = (size_t)(3 * b) * HW + crow;
        out[ob + e - 1]          = (aA0.x + aA0.y) * iA;
        out[ob + HW + e - 1]     = (aA1.x + aA1.y) * iA;
        out[ob + 2 * HW + e - 1] = (aA2.x + aA2.y) * iA;
        out[ob + e]              = (aB0.x + aB0.y) * iB;
        out[ob + HW + e]         = (aB1.x + aB1.y) * iB;
        out[ob + 2 * HW + e]     = (aB2.x + aB2.y) * iB;
    } else {
        // ---- border path: columns {0,1,2,509,510,511}, all rows/batches ----
        int idx  = (blk - BB * HH) * 256 + threadIdx.x;   // exactly 24576 total
        int ci   = idx % 6;
        int rest = idx / 6;
        int y = rest & 511;
        int b = rest >> 9;
        int x = ci < 3 ? ci : 506 + ci;

        const float* __restrict__ p0 = in + (size_t)(3 * b) * HW;
        const float* __restrict__ p1 = p0 + HW;
        const float* __restrict__ p2 = p1 + HW;
        int cidx = y * WW + x;
        float c0 = p0[cidx], c1 = p1[cidx], c2 = p2[cidx];
        float n0 = 0.f, n1 = 0.f, n2 = 0.f, dn = 0.f;
        #pragma unroll
        for (int dy = 0; dy < 7; ++dy) {
            int rbase = reflect512(y + dy - 3) * WW;
            float wy = swx(dy - 3);
            #pragma unroll
            for (int dx = 0; dx < 7; ++dx) {
                int o = rbase + reflect512(x + dx - 3);
                float q0 = p0[o], q1 = p1[o], q2 = p2[o];
                float d  = fabsf(q0 - c0) + fabsf(q1 - c1) + fabsf(q2 - c2);
                float d2 = d * d;
                float w  = wy * swx(dx - 3) * fmaf(fmaf(C2S, d2, C1S), d2, 1.0f);
                n0 += w * q0; n1 += w * q1; n2 += w * q2; dn += w;
            }
        }
        float inv = 1.0f / dn;
        size_t ob = (size_t)(3 * b) * HW + cidx;
        out[ob] = n0 * inv; out[ob + HW] = n1 * inv; out[ob + 2 * HW] = n2 * inv;
    }
}

extern "C" void kernel_launch(void* const* d_in, const int* in_sizes, int n_in,
                              void* d_out, int out_size, void* d_ws, size_t ws_size,
                              hipStream_t stream) {
    const float* in = (const float*)d_in[0];
    float* out = (float*)d_out;
    // 4096 interior blocks (one per image row) + 96 border blocks
    int blocks = BB * HH + (BB * HH * 6) / 256;   // 4096 + 96 = 4192
    bilateral_pk2<<<blocks, 256, 0, stream>>>(in, out);
}

// Round 15
// 43.280 us; speedup vs baseline: 1.1792x; 1.1286x over previous
//
#include <hip/hip_runtime.h>

#define BB 8
#define HH 512
#define WW 512
#define HW (HH * WW)

typedef float f32x2 __attribute__((ext_vector_type(2)));

__device__ __forceinline__ int reflect512(int v) {
    v = v < 0 ? -v : v;
    return v >= 512 ? 1022 - v : v;
}

// unnormalized 1-D spatial gaussian (sigma=21); out-of-window -> 0 (mask)
__device__ __forceinline__ float swx(int dx) {
    const float SW[7] = {0.98984784f, 0.99547514f, 0.99886688f, 1.0f,
                         0.99886688f, 0.99547514f, 0.98984784f};
    return (dx < -3 || dx > 3) ? 0.0f : SW[dx + 3];
}

// exp(-0.005*d2) ~= 1 + C1*d2 + C2*d2^2, |err| <= 1.5e-5 for d<=3 (R5-proven)
#define C1S (-5.0e-3f)
#define C2S (1.25e-5f)

// Thread owns a 2x2 quad: pixels (y0, e-1),(y0, e),(y0+1, e-1),(y0+1, e).
// 8-row window loaded once feeds both output rows (VMEM/px 42 -> 27);
// explicit q[r&1] double-buffer keeps a full row (12 loads) in flight.
__global__ __launch_bounds__(128) void bilateral_quad(const float* __restrict__ in,
                                                      float* __restrict__ out) {
    const int blk = blockIdx.x;
    if (blk < 4096) {
        // XCD swizzle (R13: without it FETCH=89MB; with it 14MB): blk%8 = XCD,
        // so XCD k walks image k in row-pair order.
        const int swz  = (blk & 7) * 512 + (blk >> 3);
        const int b    = swz >> 9;
        const int rest = swz & 511;
        const int y0   = (rest >> 1) * 2;     // top output row (even)
        const int h    = rest & 1;            // column half
        const int p    = threadIdx.x;
        const int nact = h ? 126 : 127;
        if (p >= nact) return;                // no barriers used
        const int e  = 4 + 254 * h + 2 * p;   // B col; A = e-1
        const int xb = e - 4;                 // leftmost loaded col (8B aligned)

        const float* __restrict__ p0 = in + (size_t)(3 * b) * HW;
        const float* __restrict__ p1 = p0 + HW;
        const float* __restrict__ p2 = p1 + HW;

        // centers for both rows (rows y0, y0+1 are real rows, no reflect)
        float cA[2][3], cB[2][3];
        #pragma unroll
        for (int row = 0; row < 2; ++row) {
            const int rb = (y0 + row) * WW + xb;
            f32x2 m0 = *(const f32x2*)(p0 + rb + 2);   // cols e-2,e-1
            f32x2 m1 = *(const f32x2*)(p1 + rb + 2);
            f32x2 m2 = *(const f32x2*)(p2 + rb + 2);
            f32x2 g0 = *(const f32x2*)(p0 + rb + 4);   // cols e,e+1
            f32x2 g1 = *(const f32x2*)(p1 + rb + 4);
            f32x2 g2 = *(const f32x2*)(p2 + rb + 4);
            cA[row][0] = m0.y; cA[row][1] = m1.y; cA[row][2] = m2.y;
            cB[row][0] = g0.x; cB[row][1] = g1.x; cB[row][2] = g2.x;
        }

        // accumulators [row][arm A/B]
        f32x2 aN0[2][2], aN1[2][2], aN2[2][2], aD[2][2];
        #pragma unroll
        for (int row = 0; row < 2; ++row)
            #pragma unroll
            for (int a = 0; a < 2; ++a) {
                aN0[row][a] = (f32x2){0.f, 0.f}; aN1[row][a] = (f32x2){0.f, 0.f};
                aN2[row][a] = (f32x2){0.f, 0.f}; aD[row][a]  = (f32x2){0.f, 0.f};
            }

        // rolling window row, double-buffered on parity (static after unroll)
        f32x2 q0[2][4], q1[2][4], q2[2][4];
        {
            const int rb = reflect512(y0 - 3) * WW + xb;
            #pragma unroll
            for (int i = 0; i < 4; ++i) {
                q0[0][i] = *(const f32x2*)(p0 + rb + 2 * i);
                q1[0][i] = *(const f32x2*)(p1 + rb + 2 * i);
                q2[0][i] = *(const f32x2*)(p2 + rb + 2 * i);
            }
        }

        const f32x2 C1v = {C1S, C1S}, C2v = {C2S, C2S}, ONE = {1.f, 1.f};

        #pragma unroll
        for (int r = 0; r < 8; ++r) {          // staged rows y0-3 .. y0+4
            const int cur = r & 1, nx = cur ^ 1;
            if (r < 7) {                        // prefetch next row (in flight
                const int rb = reflect512(y0 - 2 + r) * WW + xb;  // under taps)
                #pragma unroll
                for (int i = 0; i < 4; ++i) {
                    q0[nx][i] = *(const f32x2*)(p0 + rb + 2 * i);
                    q1[nx][i] = *(const f32x2*)(p1 + rb + 2 * i);
                    q2[nx][i] = *(const f32x2*)(p2 + rb + 2 * i);
                }
            }
            #pragma unroll
            for (int i = 0; i < 4; ++i) {
                const f32x2 v0 = q0[cur][i], v1 = q1[cur][i], v2 = q2[cur][i];
                #pragma unroll
                for (int row = 0; row < 2; ++row) {
                    const int dy = r - row;     // 0-based window row for this out-row
                    if (dy < 0 || dy > 6) continue;   // statically eliminated
                    const float wj = swx(dy - 3);
                    {   // arm A: dx = {2i-3, 2i-2}; sc=0 masks dx=4
                        float dlo = fabsf(v0.x-cA[row][0]) + fabsf(v1.x-cA[row][1]) + fabsf(v2.x-cA[row][2]);
                        float dhi = fabsf(v0.y-cA[row][0]) + fabsf(v1.y-cA[row][1]) + fabsf(v2.y-cA[row][2]);
                        f32x2 dp = {dlo, dhi};
                        f32x2 d2 = dp * dp;
                        const f32x2 sc = {wj * swx(2*i-3), wj * swx(2*i-2)};
                        f32x2 t = C2v * d2 + C1v;       // pk_fma
                        f32x2 w = (t * d2 + ONE) * sc;  // pk_fma + pk_mul
                        aN0[row][0] += w * v0; aN1[row][0] += w * v1;
                        aN2[row][0] += w * v2; aD[row][0] += w;
                    }
                    {   // arm B: dx = {2i-4, 2i-3}; sc=0 masks dx=-4
                        float dlo = fabsf(v0.x-cB[row][0]) + fabsf(v1.x-cB[row][1]) + fabsf(v2.x-cB[row][2]);
                        float dhi = fabsf(v0.y-cB[row][0]) + fabsf(v1.y-cB[row][1]) + fabsf(v2.y-cB[row][2]);
                        f32x2 dp = {dlo, dhi};
                        f32x2 d2 = dp * dp;
                        const f32x2 sc = {wj * swx(2*i-4), wj * swx(2*i-3)};
                        f32x2 t = C2v * d2 + C1v;
                        f32x2 w = (t * d2 + ONE) * sc;
                        aN0[row][1] += w * v0; aN1[row][1] += w * v1;
                        aN2[row][1] += w * v2; aD[row][1] += w;
                    }
                }
            }
        }

        #pragma unroll
        for (int row = 0; row < 2; ++row) {
            const float iA = 1.0f / (aD[row][0].x + aD[row][0].y);
            const float iB = 1.0f / (aD[row][1].x + aD[row][1].y);
            size_t ob = (size_t)(3 * b) * HW + (size_t)(y0 + row) * WW;
            out[ob + e - 1]          = (aN0[row][0].x + aN0[row][0].y) * iA;
            out[ob + HW + e - 1]     = (aN1[row][0].x + aN1[row][0].y) * iA;
            out[ob + 2 * HW + e - 1] = (aN2[row][0].x + aN2[row][0].y) * iA;
            out[ob + e]              = (aN0[row][1].x + aN0[row][1].y) * iB;
            out[ob + HW + e]         = (aN1[row][1].x + aN1[row][1].y) * iB;
            out[ob + 2 * HW + e]     = (aN2[row][1].x + aN2[row][1].y) * iB;
        }
    } else {
        // ---- border path: columns {0,1,2,509,510,511}, all rows/batches ----
        int idx  = (blk - 4096) * 128 + threadIdx.x;   // exactly 24576
        int ci   = idx % 6;
        int rest = idx / 6;
        int y = rest & 511;
        int b = rest >> 9;
        int x = ci < 3 ? ci : 506 + ci;

        const float* __restrict__ p0 = in + (size_t)(3 * b) * HW;
        const float* __restrict__ p1 = p0 + HW;
        const float* __restrict__ p2 = p1 + HW;
        int cidx = y * WW + x;
        float c0 = p0[cidx], c1 = p1[cidx], c2 = p2[cidx];
        float n0 = 0.f, n1 = 0.f, n2 = 0.f, dn = 0.f;
        #pragma unroll
        for (int dy = 0; dy < 7; ++dy) {
            int rbase = reflect512(y + dy - 3) * WW;
            float wy = swx(dy - 3);
            #pragma unroll
            for (int dx = 0; dx < 7; ++dx) {
                int o = rbase + reflect512(x + dx - 3);
                float q0 = p0[o], q1 = p1[o], q2 = p2[o];
                float d  = fabsf(q0 - c0) + fabsf(q1 - c1) + fabsf(q2 - c2);
                float d2 = d * d;
                float w  = wy * swx(dx - 3) * fmaf(fmaf(C2S, d2, C1S), d2, 1.0f);
                n0 += w * q0; n1 += w * q1; n2 += w * q2; dn += w;
            }
        }
        float inv = 1.0f / dn;
        size_t ob = (size_t)(3 * b) * HW + cidx;
        out[ob] = n0 * inv; out[ob + HW] = n1 * inv; out[ob + 2 * HW] = n2 * inv;
    }
}

extern "C" void kernel_launch(void* const* d_in, const int* in_sizes, int n_in,
                              void* d_out, int out_size, void* d_ws, size_t ws_size,
                              hipStream_t stream) {
    const float* in = (const float*)d_in[0];
    float* out = (float*)d_out;
    // 4096 interior blocks (8 img x 256 row-pairs x 2 col-halves) + 192 border
    int blocks = 4096 + 192;
    bilateral_quad<<<blocks, 128, 0, stream>>>(in, out);
}